// Round 1
// baseline (195.865 us; speedup 1.0000x reference)
//
#include <hip/hip_runtime.h>

// QuantumSpectralConv: x[4,128,128,64] f32, W[16,16,64,64,4] complex (re/im planes)
//   x_ft = DFT_{H,W}(x) truncated to 16x16 modes
//   out_modes[b,k,m,o] = sum_{n,c} x_ft[b,k,n,c] * (sum_s W[m,n,c,o,s]) / sqrt(4)
//   out = Re(iDFT zero-padded)  -> [4,128,128,64] f32
//
// Pipeline: trig-init -> DFT_w -> DFT_h -> complex GEMM (K split by n, atomic
// reduce) -> iDFT_h -> iDFT_w.  All fp32 VALU (no fp32 MFMA on CDNA4).

static constexpr int BATCH = 4;

// float offsets into workspace
static constexpr size_t TRIG_OFF = 0;                    // 128 float2
static constexpr size_t TMP_OFF  = 1024;                 // tmp1 / u: 1,048,576 floats (4MB)
static constexpr size_t XFT_OFF  = TMP_OFF + 1048576;    // 131,072 floats
static constexpr size_t OM_OFF   = XFT_OFF + 131072;     // 131,072 floats
// total: ~5.25 MB of ws

// trig[t] = (cos, sin)(2*pi*t/128)
__global__ __launch_bounds__(128) void k_init_trig(float2* __restrict__ trig) {
    int t = threadIdx.x;
    float s, c;
    sincosf(6.283185307179586f * (float)t * (1.0f / 128.0f), &s, &c);
    trig[t] = make_float2(c, s);
}

// DFT over W: tmp1[b,h,n,c] = sum_w x[b,h,w,c] * e^{-2pi i n w/128}, n<16
// block per (b,h) = 512 blocks, 256 thr. Thread: one n (tid>>4), 4 c's (tid&15).
// x row staged in LDS as [w][c4] float4; trig from global (L1) to keep LDS pipe free.
__global__ __launch_bounds__(256) void k_dft_w(const float* __restrict__ x,
                                               const float2* __restrict__ trig,
                                               float2* __restrict__ tmp1) {
    __shared__ float4 xs[2048];                       // [128 w][16 c4] = 32KB
    const int bid = blockIdx.x;                       // b*128 + h
    const float4* x4 = reinterpret_cast<const float4*>(x) + (size_t)bid * 2048;
    #pragma unroll
    for (int i = 0; i < 8; ++i) xs[threadIdx.x + 256 * i] = x4[threadIdx.x + 256 * i];
    __syncthreads();
    const int n  = threadIdx.x >> 4;
    const int c4 = threadIdx.x & 15;
    float4 ar = make_float4(0.f, 0.f, 0.f, 0.f);
    float4 ai = make_float4(0.f, 0.f, 0.f, 0.f);
    int t = 0;                                        // t = (n*w) & 127
    #pragma unroll 8
    for (int w = 0; w < 128; ++w) {
        const float4 v  = xs[w * 16 + c4];            // 2-way bank alias: free
        const float2 tw = trig[t];
        t = (t + n) & 127;
        ar.x += v.x * tw.x; ai.x -= v.x * tw.y;
        ar.y += v.y * tw.x; ai.y -= v.y * tw.y;
        ar.z += v.z * tw.x; ai.z -= v.z * tw.y;
        ar.w += v.w * tw.x; ai.w -= v.w * tw.y;
    }
    float4* o = reinterpret_cast<float4*>(tmp1 + ((size_t)bid * 16 + n) * 64 + c4 * 4);
    o[0] = make_float4(ar.x, ai.x, ar.y, ai.y);
    o[1] = make_float4(ar.z, ai.z, ar.w, ai.w);
}

// DFT over H: xft[(b*16+k)*1024 + n*64+c] = sum_h tmp1[b,h,n,c] * e^{-2pi i k h/128}
// one thread per output (65536), k wave-uniform -> trig load is a broadcast.
__global__ __launch_bounds__(256) void k_dft_h(const float2* __restrict__ tmp1,
                                               const float2* __restrict__ trig,
                                               float2* __restrict__ xft) {
    const int tid = blockIdx.x * 256 + threadIdx.x;
    const int c = tid & 63;
    const int n = (tid >> 6) & 15;
    const int k = (tid >> 10) & 15;
    const int b = tid >> 14;
    const float2* src = tmp1 + (size_t)b * 131072 + n * 64 + c;  // + h*1024
    float2 acc = make_float2(0.f, 0.f);
    int t = 0;                                        // t = (k*h) & 127
    #pragma unroll 8
    for (int h = 0; h < 128; ++h) {
        const float2 a  = src[(size_t)h * 1024];
        const float2 tw = trig[t];
        t = (t + k) & 127;
        acc.x += a.x * tw.x + a.y * tw.y;             // (ar+iai)(c-is)
        acc.y += a.y * tw.x - a.x * tw.y;
    }
    xft[(size_t)(b * 16 + k) * 1024 + n * 64 + c] = acc;
}

// Complex GEMM with fused Schmidt reduction:
//   omT[(m*64+o)*64 + row] += sum_{c} xft[row][n*64+c] * Bn[c][o]
//   Bn[c][o] = sum_s (wr + i wi)[m,n,c,o,s] * 0.5   (0.5 = 1/sqrt(4))
// grid 512 = (m, o-half, n); K split by n -> fp32 atomicAdd reduce (omT pre-zeroed).
// Thread tile 4 rows x 2 cols; As padded to 66, Bs to 34 (even -> b128-aligned).
__global__ __launch_bounds__(256) void k_gemm(const float2* __restrict__ xft,
                                              const float* __restrict__ wr,
                                              const float* __restrict__ wi,
                                              float* __restrict__ omT) {
    __shared__ float2 As[64 * 66];                    // [kk(c)][row] 33.8KB
    __shared__ float2 Bs[64 * 34];                    // [kk(c)][o]   17.4KB
    const int bid = blockIdx.x;
    const int n  = bid & 15;
    const int oh = (bid >> 4) & 1;
    const int m  = bid >> 5;
    const int o0 = oh * 32;
    #pragma unroll
    for (int i = 0; i < 16; ++i) {                    // stage A chunk (coalesced)
        const int idx = threadIdx.x + 256 * i;
        const int row = idx >> 6, kk = idx & 63;
        As[kk * 66 + row] = xft[(size_t)row * 1024 + n * 64 + kk];
    }
    #pragma unroll
    for (int i = 0; i < 8; ++i) {                     // stage B: raw weights, sum s
        const int idx = threadIdx.x + 256 * i;
        const int cc = idx >> 5, o = idx & 31;
        const size_t wb = ((size_t)((m * 16 + n) * 64 + cc) * 64 + o0 + o) * 4;
        const float4 r4 = *reinterpret_cast<const float4*>(wr + wb);
        const float4 i4 = *reinterpret_cast<const float4*>(wi + wb);
        Bs[cc * 34 + o] = make_float2((r4.x + r4.y + r4.z + r4.w) * 0.5f,
                                      (i4.x + i4.y + i4.z + i4.w) * 0.5f);
    }
    __syncthreads();
    const int ri = threadIdx.x & 15;                  // rows 4ri..4ri+3
    const int ci = threadIdx.x >> 4;                  // cols 2ci..2ci+1
    float accr[4][2] = {}, acci[4][2] = {};
    #pragma unroll 4
    for (int kk = 0; kk < 64; ++kk) {
        const float4 a01 = *reinterpret_cast<const float4*>(&As[kk * 66 + 4 * ri]);
        const float4 a23 = *reinterpret_cast<const float4*>(&As[kk * 66 + 4 * ri + 2]);
        const float4 bb  = *reinterpret_cast<const float4*>(&Bs[kk * 34 + 2 * ci]);
        const float arr[4] = {a01.x, a01.z, a23.x, a23.z};
        const float aii[4] = {a01.y, a01.w, a23.y, a23.w};
        #pragma unroll
        for (int r = 0; r < 4; ++r) {
            accr[r][0] += arr[r] * bb.x - aii[r] * bb.y;
            acci[r][0] += arr[r] * bb.y + aii[r] * bb.x;
            accr[r][1] += arr[r] * bb.z - aii[r] * bb.w;
            acci[r][1] += arr[r] * bb.w + aii[r] * bb.z;
        }
    }
    #pragma unroll
    for (int r = 0; r < 4; ++r) {
        const int row = 4 * ri + r;
        #pragma unroll
        for (int cc2 = 0; cc2 < 2; ++cc2) {
            const int col = m * 64 + o0 + 2 * ci + cc2;
            atomicAdd(&omT[((size_t)col * 64 + row) * 2 + 0], accr[r][cc2]);
            atomicAdd(&omT[((size_t)col * 64 + row) * 2 + 1], acci[r][cc2]);
        }
    }
}

// inverse over H: u[b,h,m,o] = sum_{k<16} omT[(m*64+o)*64 + b*16+k] * e^{+2pi i k h/128}
// grid 256 = (b, m, h-quarter); per-thread om strip (16 complex) lives in registers.
__global__ __launch_bounds__(256) void k_ifft_h(const float2* __restrict__ omT,
                                                const float2* __restrict__ trig,
                                                float2* __restrict__ u) {
    const int bid = blockIdx.x;
    const int hq = bid & 3;
    const int m  = (bid >> 2) & 15;
    const int b  = bid >> 6;
    const int o  = threadIdx.x & 63;
    const int hs = threadIdx.x >> 6;                  // wave-uniform
    const float2* src = omT + ((size_t)(m * 64 + o) * 64 + b * 16);
    float2 v[16];
    #pragma unroll
    for (int k4 = 0; k4 < 8; ++k4) {
        const float4 q = reinterpret_cast<const float4*>(src)[k4];
        v[2 * k4]     = make_float2(q.x, q.y);
        v[2 * k4 + 1] = make_float2(q.z, q.w);
    }
    #pragma unroll
    for (int i = 0; i < 8; ++i) {
        const int h = hq * 32 + hs * 8 + i;
        float re = 0.f, im = 0.f;
        int t = 0;                                    // t = (k*h) & 127
        #pragma unroll
        for (int k = 0; k < 16; ++k) {
            const float2 tw = trig[t];
            t = (t + h) & 127;
            re += v[k].x * tw.x - v[k].y * tw.y;      // (or+ioi)(c+is)
            im += v[k].x * tw.y + v[k].y * tw.x;
        }
        u[((size_t)(b * 128 + h) * 16 + m) * 64 + o] = make_float2(re, im);
    }
}

// inverse over W + real part + 1/(128*128):
//   out[b,h,w,o] = (1/16384) * sum_{m<16} Re(u[b,h,m,o] * e^{+2pi i m w/128})
// block per (b,h) = 512; the 16x4 complex u-slice per thread lives in registers.
__global__ __launch_bounds__(256) void k_ifft_w(const float2* __restrict__ u,
                                                const float2* __restrict__ trig,
                                                float* __restrict__ out) {
    const int bid = blockIdx.x;                       // b*128 + h
    const int o4 = threadIdx.x & 15;                  // 4 o's
    const int wg = threadIdx.x >> 4;                  // 8 w's
    const float2* ub = u + (size_t)bid * 1024 + o4 * 4;
    float2 v[16][4];
    #pragma unroll
    for (int mm = 0; mm < 16; ++mm) {
        const float4 q0 = *reinterpret_cast<const float4*>(ub + (size_t)mm * 64);
        const float4 q1 = *reinterpret_cast<const float4*>(ub + (size_t)mm * 64 + 2);
        v[mm][0] = make_float2(q0.x, q0.y);
        v[mm][1] = make_float2(q0.z, q0.w);
        v[mm][2] = make_float2(q1.x, q1.y);
        v[mm][3] = make_float2(q1.z, q1.w);
    }
    const float inv = 1.0f / 16384.0f;
    #pragma unroll
    for (int i = 0; i < 8; ++i) {
        const int w = wg * 8 + i;
        float4 acc = make_float4(0.f, 0.f, 0.f, 0.f);
        int t = 0;                                    // t = (m*w) & 127
        #pragma unroll
        for (int mm = 0; mm < 16; ++mm) {
            const float2 tw = trig[t];
            t = (t + w) & 127;
            acc.x += v[mm][0].x * tw.x - v[mm][0].y * tw.y;
            acc.y += v[mm][1].x * tw.x - v[mm][1].y * tw.y;
            acc.z += v[mm][2].x * tw.x - v[mm][2].y * tw.y;
            acc.w += v[mm][3].x * tw.x - v[mm][3].y * tw.y;
        }
        acc.x *= inv; acc.y *= inv; acc.z *= inv; acc.w *= inv;
        *reinterpret_cast<float4*>(out + ((size_t)bid * 128 + w) * 64 + o4 * 4) = acc;
    }
}

extern "C" void kernel_launch(void* const* d_in, const int* in_sizes, int n_in,
                              void* d_out, int out_size, void* d_ws, size_t ws_size,
                              hipStream_t stream) {
    const float* x  = (const float*)d_in[0];
    const float* wr = (const float*)d_in[1];
    const float* wi = (const float*)d_in[2];
    float* out = (float*)d_out;
    float* ws  = (float*)d_ws;

    float2* trig = (float2*)(ws + TRIG_OFF);
    float2* tmp1 = (float2*)(ws + TMP_OFF);   // tmp1, later reused as u
    float2* xft  = (float2*)(ws + XFT_OFF);
    float*  omT  = ws + OM_OFF;

    // zero the atomic accumulator (ws is poisoned 0xAA before every call)
    hipMemsetAsync(omT, 0, 131072 * sizeof(float), stream);
    k_init_trig<<<1, 128, 0, stream>>>(trig);
    k_dft_w<<<BATCH * 128, 256, 0, stream>>>(x, trig, tmp1);
    k_dft_h<<<256, 256, 0, stream>>>(tmp1, trig, xft);
    k_gemm<<<512, 256, 0, stream>>>(xft, wr, wi, omT);
    k_ifft_h<<<256, 256, 0, stream>>>((const float2*)omT, trig, tmp1 /* = u */);
    k_ifft_w<<<BATCH * 128, 256, 0, stream>>>(tmp1 /* = u */, trig, out);
}

// Round 4
// 147.002 us; speedup vs baseline: 1.3324x; 1.3324x over previous
//
#include <hip/hip_runtime.h>

// QuantumSpectralConv: x[4,128,128,64] f32, W[16,16,64,64,4] re/im planes.
//   x_ft = DFT_{H,W}(x) truncated to 16x16 modes
//   om[b,k,m,o] = sum_{n,c} x_ft[b,k,n,c] * (sum_s W[m,n,c,o,s]) / 2
//   out = Re(iDFT zero-padded)  -> [4,128,128,64] f32
//
// Pipeline (6 kernels, no atomics, no memset):
//   dft_w -> dft_h -> gemm (split-K by n-octet, private partials)
//   -> reduce -> ifft_h -> ifft_w
// Twiddle tables built per-block in LDS (sincosf); no separate trig kernel.
// k_gemm stages one n-slab (K=64) at a time: 50 KB LDS -> 3 blocks/CU.

static constexpr int BATCH = 4;

// float offsets into workspace (total 5.25 MB)
static constexpr size_t XFT_OFF = 0;          // 131,072 floats (65,536 complex)
static constexpr size_t OM_OFF  = 131072;     // 131,072 floats
static constexpr size_t BIG_OFF = 262144;     // 1,048,576 floats: tmp1 / P / u
//   tmp1 live dft_w->dft_h; P live gemm->reduce; u live ifft_h->ifft_w

// twl[t] = (cos, sin)(2*pi*t/128), built by threads 0..127
__device__ __forceinline__ void init_trig_lds(float2* twl) {
    if (threadIdx.x < 128) {
        float s, c;
        sincosf(6.283185307179586f * (float)threadIdx.x * 0.0078125f, &s, &c);
        twl[threadIdx.x] = make_float2(c, s);
    }
}

// DFT over W: tmp1[b,h,n,c] = sum_w x[b,h,w,c] * e^{-2pi i n w/128}, n<16
// block per (b,h) = 512 blocks. Thread: one n (tid>>4), 4 c's (tid&15).
__global__ __launch_bounds__(256) void k_dft_w(const float* __restrict__ x,
                                               float2* __restrict__ tmp1) {
    __shared__ float4 xs[2048];                       // [128 w][16 c4] = 32KB
    __shared__ float2 twl[128];
    init_trig_lds(twl);
    const int bid = blockIdx.x;                       // b*128 + h
    const float4* x4 = reinterpret_cast<const float4*>(x) + (size_t)bid * 2048;
    #pragma unroll
    for (int i = 0; i < 8; ++i) xs[threadIdx.x + 256 * i] = x4[threadIdx.x + 256 * i];
    __syncthreads();
    const int n  = threadIdx.x >> 4;
    const int c4 = threadIdx.x & 15;
    float4 ar = make_float4(0.f, 0.f, 0.f, 0.f);
    float4 ai = make_float4(0.f, 0.f, 0.f, 0.f);
    int t = 0;                                        // t = (n*w) & 127
    #pragma unroll 8
    for (int w = 0; w < 128; ++w) {
        const float4 v  = xs[w * 16 + c4];
        const float2 tw = twl[t];
        t = (t + n) & 127;
        ar.x += v.x * tw.x; ai.x -= v.x * tw.y;
        ar.y += v.y * tw.x; ai.y -= v.y * tw.y;
        ar.z += v.z * tw.x; ai.z -= v.z * tw.y;
        ar.w += v.w * tw.x; ai.w -= v.w * tw.y;
    }
    float4* o = reinterpret_cast<float4*>(tmp1 + ((size_t)bid * 16 + n) * 64 + c4 * 4);
    o[0] = make_float4(ar.x, ai.x, ar.y, ai.y);
    o[1] = make_float4(ar.z, ai.z, ar.w, ai.w);
}

// DFT over H: xft[(b*16+k)*1024 + n*64+c] = sum_h tmp1[b,h,n,c] * e^{-2pi i k h/128}
// one thread per output; k,b are block-uniform -> twiddle LDS loads broadcast.
__global__ __launch_bounds__(256) void k_dft_h(const float2* __restrict__ tmp1,
                                               float2* __restrict__ xft) {
    __shared__ float2 twl[128];
    init_trig_lds(twl);
    __syncthreads();
    const int tid = blockIdx.x * 256 + threadIdx.x;
    const int c = tid & 63;
    const int n = (tid >> 6) & 15;
    const int k = (tid >> 10) & 15;
    const int b = tid >> 14;
    const float2* src = tmp1 + (size_t)b * 131072 + n * 64 + c;  // + h*1024
    float2 acc = make_float2(0.f, 0.f);
    int t = 0;                                        // t = (k*h) & 127
    #pragma unroll 8
    for (int h = 0; h < 128; ++h) {
        const float2 a  = src[(size_t)h * 1024];
        const float2 tw = twl[t];
        t = (t + k) & 127;
        acc.x += a.x * tw.x + a.y * tw.y;             // (ar+iai)(c-is)
        acc.y += a.y * tw.x - a.x * tw.y;
    }
    xft[(size_t)(b * 16 + k) * 1024 + n * 64 + c] = acc;
}

// Complex GEMM with fused Schmidt reduction, atomic-free split-K:
//   grid 256 = (m 16, oh 2, noct 8); block loops over its 2 n-slabs (K=64 each),
//   staging 50KB LDS per slab (3 blocks/CU), accumulating out tile
//   [64 rows][32 o] in registers; writes private partial P[bid][row][oo].
//   Bn[c][o] = sum_s (wr + i wi)[m,n,c,o,s] * 0.5
__global__ __launch_bounds__(256) void k_gemm(const float2* __restrict__ xft,
                                              const float* __restrict__ wr,
                                              const float* __restrict__ wi,
                                              float2* __restrict__ P) {
    __shared__ float2 As[64 * 66];                    // [kk][row] 33.8KB
    __shared__ float2 Bs[64 * 34];                    // [kk][oo]  17.0KB
    const int bid  = blockIdx.x;                      // (m*2+oh)*8 + noct
    const int noct = bid & 7;
    const int oh   = (bid >> 3) & 1;
    const int m    = bid >> 4;
    const int ci = threadIdx.x & 15;                  // o pair: 2ci, 2ci+1
    const int ri = threadIdx.x >> 4;                  // rows 4ri..4ri+3
    float accr[4][2] = {}, acci[4][2] = {};
    for (int nn = 0; nn < 2; ++nn) {
        const int n = noct * 2 + nn;
        // stage A: xft[row][n*64 + kk], float4 = 2 complex per load
        #pragma unroll
        for (int i = 0; i < 8; ++i) {
            const int idx = threadIdx.x + 256 * i;    // 2048
            const int row = idx >> 5, k2 = idx & 31;
            const float4 q = *reinterpret_cast<const float4*>(
                &xft[(size_t)row * 1024 + n * 64 + 2 * k2]);
            As[(2 * k2) * 66 + row]     = make_float2(q.x, q.y);
            As[(2 * k2 + 1) * 66 + row] = make_float2(q.z, q.w);
        }
        // stage B: raw weights, sum s (coalesced float4 over s)
        #pragma unroll
        for (int i = 0; i < 8; ++i) {
            const int idx = threadIdx.x + 256 * i;    // 2048
            const int cc = idx >> 5, oo = idx & 31;
            const size_t wb = ((size_t)((m * 16 + n) * 64 + cc) * 64 + oh * 32 + oo) * 4;
            const float4 r4 = *reinterpret_cast<const float4*>(wr + wb);
            const float4 i4 = *reinterpret_cast<const float4*>(wi + wb);
            Bs[cc * 34 + oo] = make_float2((r4.x + r4.y + r4.z + r4.w) * 0.5f,
                                           (i4.x + i4.y + i4.z + i4.w) * 0.5f);
        }
        __syncthreads();
        #pragma unroll 8
        for (int kk = 0; kk < 64; ++kk) {
            const float4 a01 = *reinterpret_cast<const float4*>(&As[kk * 66 + 4 * ri]);
            const float4 a23 = *reinterpret_cast<const float4*>(&As[kk * 66 + 4 * ri + 2]);
            const float4 bb  = *reinterpret_cast<const float4*>(&Bs[kk * 34 + 2 * ci]);
            const float arr[4] = {a01.x, a01.z, a23.x, a23.z};
            const float aii[4] = {a01.y, a01.w, a23.y, a23.w};
            #pragma unroll
            for (int r = 0; r < 4; ++r) {
                accr[r][0] += arr[r] * bb.x - aii[r] * bb.y;
                acci[r][0] += arr[r] * bb.y + aii[r] * bb.x;
                accr[r][1] += arr[r] * bb.z - aii[r] * bb.w;
                acci[r][1] += arr[r] * bb.w + aii[r] * bb.z;
            }
        }
        __syncthreads();
    }
    float2* Pb = P + (size_t)bid * 2048;              // [row 64][oo 32]
    #pragma unroll
    for (int r = 0; r < 4; ++r) {
        const int row = 4 * ri + r;
        *reinterpret_cast<float4*>(&Pb[row * 32 + 2 * ci]) =
            make_float4(accr[r][0], acci[r][0], accr[r][1], acci[r][1]);
    }
}

// reduce over the 8 n-octet partials: om[row*1024 + m*64 + o]
__global__ __launch_bounds__(256) void k_reduce(const float2* __restrict__ P,
                                                float2* __restrict__ om) {
    const int gtid = blockIdx.x * 256 + threadIdx.x;  // 65,536
    const int o   = gtid & 63;
    const int mm  = (gtid >> 6) & 15;
    const int row = gtid >> 10;
    const int oh = o >> 5, oo = o & 31;
    const float2* p = P + (size_t)((mm * 2 + oh) * 8) * 2048 + row * 32 + oo;
    float2 acc = make_float2(0.f, 0.f);
    #pragma unroll
    for (int nq = 0; nq < 8; ++nq) {
        const float2 v = p[(size_t)nq * 2048];
        acc.x += v.x; acc.y += v.y;
    }
    om[(size_t)row * 1024 + mm * 64 + o] = acc;
}

// inverse over H: u[b,h,m,o] = sum_{k<16} om[(b*16+k)*1024+m*64+o] * e^{+2pi i k h/128}
// grid 256 = (b, m, h-quarter); om strip (16 complex) in registers.
__global__ __launch_bounds__(256) void k_ifft_h(const float2* __restrict__ om,
                                                float2* __restrict__ u) {
    __shared__ float2 twl[128];
    init_trig_lds(twl);
    const int bid = blockIdx.x;
    const int hq = bid & 3;
    const int m  = (bid >> 2) & 15;
    const int b  = bid >> 6;
    const int o  = threadIdx.x & 63;
    const int hs = threadIdx.x >> 6;                  // wave-uniform
    __syncthreads();
    float2 v[16];
    #pragma unroll
    for (int k = 0; k < 16; ++k)
        v[k] = om[(size_t)(b * 16 + k) * 1024 + m * 64 + o];
    #pragma unroll
    for (int i = 0; i < 8; ++i) {
        const int h = hq * 32 + hs * 8 + i;
        float re = 0.f, im = 0.f;
        int t = 0;                                    // t = (k*h) & 127, wave-uniform
        #pragma unroll
        for (int k = 0; k < 16; ++k) {
            const float2 tw = twl[t];
            t = (t + h) & 127;
            re += v[k].x * tw.x - v[k].y * tw.y;      // (or+ioi)(c+is)
            im += v[k].x * tw.y + v[k].y * tw.x;
        }
        u[((size_t)(b * 128 + h) * 16 + m) * 64 + o] = make_float2(re, im);
    }
}

// inverse over W + real part + 1/(128*128):
//   out[b,h,w,o] = (1/16384) * sum_{m<16} Re(u[b,h,m,o] * e^{+2pi i m w/128})
__global__ __launch_bounds__(256) void k_ifft_w(const float2* __restrict__ u,
                                                float* __restrict__ out) {
    __shared__ float2 twl[128];
    init_trig_lds(twl);
    const int bid = blockIdx.x;                       // b*128 + h
    const int o4 = threadIdx.x & 15;                  // 4 o's
    const int wg = threadIdx.x >> 4;                  // 8 w's
    __syncthreads();
    const float2* ub = u + (size_t)bid * 1024 + o4 * 4;
    float2 v[16][4];
    #pragma unroll
    for (int mm = 0; mm < 16; ++mm) {
        const float4 q0 = *reinterpret_cast<const float4*>(ub + (size_t)mm * 64);
        const float4 q1 = *reinterpret_cast<const float4*>(ub + (size_t)mm * 64 + 2);
        v[mm][0] = make_float2(q0.x, q0.y);
        v[mm][1] = make_float2(q0.z, q0.w);
        v[mm][2] = make_float2(q1.x, q1.y);
        v[mm][3] = make_float2(q1.z, q1.w);
    }
    const float inv = 1.0f / 16384.0f;
    #pragma unroll
    for (int i = 0; i < 8; ++i) {
        const int w = wg * 8 + i;
        float4 acc = make_float4(0.f, 0.f, 0.f, 0.f);
        int t = 0;                                    // t = (m*w) & 127
        #pragma unroll
        for (int mm = 0; mm < 16; ++mm) {
            const float2 tw = twl[t];
            t = (t + w) & 127;
            acc.x += v[mm][0].x * tw.x - v[mm][0].y * tw.y;
            acc.y += v[mm][1].x * tw.x - v[mm][1].y * tw.y;
            acc.z += v[mm][2].x * tw.x - v[mm][2].y * tw.y;
            acc.w += v[mm][3].x * tw.x - v[mm][3].y * tw.y;
        }
        acc.x *= inv; acc.y *= inv; acc.z *= inv; acc.w *= inv;
        *reinterpret_cast<float4*>(out + ((size_t)bid * 128 + w) * 64 + o4 * 4) = acc;
    }
}

extern "C" void kernel_launch(void* const* d_in, const int* in_sizes, int n_in,
                              void* d_out, int out_size, void* d_ws, size_t ws_size,
                              hipStream_t stream) {
    const float* x  = (const float*)d_in[0];
    const float* wr = (const float*)d_in[1];
    const float* wi = (const float*)d_in[2];
    float* out = (float*)d_out;
    float* ws  = (float*)d_ws;

    float2* xft = (float2*)(ws + XFT_OFF);
    float2* om  = (float2*)(ws + OM_OFF);
    float2* big = (float2*)(ws + BIG_OFF);            // tmp1 / P / u

    k_dft_w <<<BATCH * 128, 256, 0, stream>>>(x, big);
    k_dft_h <<<256, 256, 0, stream>>>(big, xft);
    k_gemm  <<<256, 256, 0, stream>>>(xft, wr, wi, big);
    k_reduce<<<256, 256, 0, stream>>>(big, om);
    k_ifft_h<<<256, 256, 0, stream>>>(om, big);
    k_ifft_w<<<BATCH * 128, 256, 0, stream>>>(big, out);
}